// Round 14
// baseline (671.109 us; speedup 1.0000x reference)
//
#include <hip/hip_runtime.h>
#include <hip/hip_bf16.h>

typedef __hip_bfloat16 BF;
typedef __attribute__((ext_vector_type(8))) short short8;
typedef __attribute__((ext_vector_type(4))) float f32x4;

#define DEV __device__ __forceinline__

// ---------------------------------------------------------------- helpers
DEV void gll16(const BF* g, BF* l) {
  __builtin_amdgcn_global_load_lds(
      (const __attribute__((address_space(1))) void*)g,
      (__attribute__((address_space(3))) void*)l, 16, 0, 0);
}

DEV unsigned short bfbits(float f) {
  BF b = __float2bfloat16(f);
  return *reinterpret_cast<unsigned short*>(&b);
}

DEV ushort4 cvt4(const float4 v) {
  return make_ushort4(bfbits(v.x), bfbits(v.y), bfbits(v.z), bfbits(v.w));
}

// rope-pair permutation: orig dim d (0..255) -> gemm column c, so that pairs
// (d, d+128) land in the same thread (acc slots n and n+2).  QK^T is invariant
// to a consistent d-permutation of Q and K, so attn consumes c-space directly.
DEV int rope_perm(int d) {
  return (d < 128) ? ((d >> 5) * 64 + (d & 31))
                   : (((d - 128) >> 5) * 64 + 32 + ((d - 128) & 31));
}

// ---------------------------------------------------------------- fused f32 -> bf16
// x, wq(perm), wk(perm), wv, wo(pad).  float4 ranges:
// x[0,3932160) wq[..7864320) wk[..9830400) wv[..11796480) wo[..15728640)
__global__ void cvt_fused(const float* __restrict__ x, const float* __restrict__ wq,
                          const float* __restrict__ wk, const float* __restrict__ wv,
                          const float* __restrict__ wo,
                          BF* __restrict__ Xbf, BF* __restrict__ Wqkv, BF* __restrict__ Wo) {
  const int stride = gridDim.x * blockDim.x;
  for (int i = blockIdx.x * blockDim.x + threadIdx.x; i < 15728640; i += stride) {
    if (i < 3932160) {
      ((ushort4*)Xbf)[i] = cvt4(((const float4*)x)[i]);
    } else if (i < 7864320) {
      const int off = i - 3932160;
      const int row = off / 960, col = off - row * 960;
      const int nrow = (row & ~255) | rope_perm(row & 255);
      ((ushort4*)Wqkv)[nrow * 960 + col] = cvt4(((const float4*)wq)[off]);
    } else if (i < 9830400) {
      const int off = i - 7864320;
      const int row = off / 960, col = off - row * 960;
      const int nrow = (row & ~255) | rope_perm(row & 255);
      ((ushort4*)(Wqkv + 4096 * 3840))[nrow * 960 + col] = cvt4(((const float4*)wk)[off]);
    } else if (i < 11796480) {
      const int off = i - 9830400;
      ((ushort4*)(Wqkv + 6144 * 3840))[off] = cvt4(((const float4*)wv)[off]);
    } else {
      const int off = i - 11796480;
      const int r = off >> 10, c = off & 1023;
      ((ushort4*)Wo)[r * 1040 + c] = cvt4(((const float4*)wo)[off]);
    }
  }
}

// ---------------------------------------------------------------- 256^2 GEMM, 4 waves (B^T)
// ROUND 14: 256 threads = 4 waves (2M x 2N), per-wave 128x128 out.  Cuts LDS
// fragment reads per CU per K-tile 192 -> 128 (the round-13 cycle model showed
// LDS drain + MFMA issue SUM under barrier lockstep; fewer reads = lower floor).
// acc = 256 VGPR, breg 32, af 16 -> ~320 < 450 no-spill line at 1 wave/SIMD.
// Same BM=BN=256, BK=64, 128 KiB LDS (2 bufs x [kk(2)][256 rows][32 cols] x2).
// Staging: unit = one kk-half of one matrix (256x32), 4 gll16/thread-block.
// vmcnt ledger: entering tile t: t landed, (t+1).kk0 in flight (8 loads);
// p1-tail vmcnt(8) lands (t+1).kk0, p3-tail vmcnt(8) lands (t+1).kk1.
#define WAITV(N)                                                                      \
  asm volatile("s_waitcnt vmcnt(" #N ")" ::: "memory");                               \
  __builtin_amdgcn_sched_barrier(0);
#define STGA(KC, BOFF)                                                                \
  _Pragma("unroll") for (int j_ = 0; j_ < 4; ++j_)                                    \
      gll16(aS + (size_t)(j_ * 64) * lda + (KC), ldsA + (BOFF) + j_ * 2048 + w * 512);
#define STGB(KC, BOFF)                                                                \
  _Pragma("unroll") for (int j_ = 0; j_ < 4; ++j_)                                    \
      gll16(bS + (size_t)(j_ * 64) * ldb + (KC), ldsB + (BOFF) + j_ * 2048 + w * 512);
#define GPHASE(MH, KK, READB, STAGE, TAIL)                                            \
  {                                                                                   \
    short8 af[4];                                                                     \
    _Pragma("unroll") for (int m_ = 0; m_ < 4; ++m_)                                  \
        af[m_] = *(const short8*)&ldsA[bX + (KK)*8192 +                               \
                                       (wm*128 + (MH)*64 + m_*16 + l15)*32 + rd8];    \
    if (READB) {                                                                      \
      _Pragma("unroll") for (int n_ = 0; n_ < 8; ++n_)                                \
          breg[n_] = *(const short8*)&ldsB[bX + (KK)*8192 +                           \
                                           (wn*128 + n_*16 + l15)*32 + rd8];          \
    }                                                                                 \
    STAGE                                                                             \
    __builtin_amdgcn_s_barrier();                                                     \
    asm volatile("s_waitcnt lgkmcnt(0)" ::: "memory");                                \
    __builtin_amdgcn_sched_barrier(0);                                                \
    __builtin_amdgcn_s_setprio(1);                                                    \
    _Pragma("unroll") for (int m_ = 0; m_ < 4; ++m_)                                  \
      _Pragma("unroll") for (int n_ = 0; n_ < 8; ++n_)                                \
        acc[(MH)*4 + m_][n_] =                                                        \
            __builtin_amdgcn_mfma_f32_16x16x32_bf16(af[m_], breg[n_],                 \
                                                    acc[(MH)*4 + m_][n_], 0, 0, 0);   \
    __builtin_amdgcn_s_setprio(0);                                                    \
    TAIL                                                                              \
    __builtin_amdgcn_s_barrier();                                                     \
  }

template <typename CT, int MODE>
DEV void gemm256_body(const BF* __restrict__ A, const BF* __restrict__ Bm,
                      CT* __restrict__ C, const int M, const int N, const int K,
                      const int lda, const int ldb,
                      BF* __restrict__ Qb, BF* __restrict__ Kb,
                      const float* __restrict__ cosl, const float* __restrict__ sinl,
                      const float* __restrict__ qw, const float* __restrict__ kw) {
  extern __shared__ __align__(16) BF lds[];
  BF* ldsA = lds;
  BF* ldsB = lds + 32768;
  const int ntl = N >> 8;
  const int mtl = M >> 8;
  int mt, nt;
  if (mtl == 16 && ntl == 32) {
    // 2-D chunked XCD raster (FETCH 507->184 MB verified round 7)
    const int x = blockIdx.x & 7;
    const int c = blockIdx.x >> 3;
    mt = ((x >> 2) << 3) + (c >> 3);
    nt = ((x & 3) << 3) + (c & 7);
  } else {
    const int cpx = gridDim.x >> 3;
    const int swzb = (blockIdx.x & 7) * cpx + (blockIdx.x >> 3);
    mt = swzb / ntl;
    nt = swzb % ntl;
  }
  const int m0 = mt << 8, n0 = nt << 8;
  const int tid = threadIdx.x, lane = tid & 63, w = tid >> 6;   // w: 0..3
  const int l15 = lane & 15, g = lane >> 4;
  const int wm = w >> 1, wn = w & 1;                            // 2M x 2N waves
  const int rd8 = (g ^ ((l15 >> 1) & 3)) << 3;                  // swizzled read slot
  const int scol = ((tid & 3) ^ ((tid >> 3) & 3)) << 3;         // inverse-swizzled src
  const BF* aS = A + (size_t)(m0 + (tid >> 2)) * lda + scol;
  const BF* bS = Bm + (size_t)(n0 + (tid >> 2)) * ldb + scol;
  const int NT = K >> 6;

  f32x4 acc[8][8];
#pragma unroll
  for (int m = 0; m < 8; ++m)
#pragma unroll
    for (int n = 0; n < 8; ++n) acc[m][n] = (f32x4){0.f, 0.f, 0.f, 0.f};
  short8 breg[8];   // B fragments, persist across mh phases

  // prologue: t0.kk0, t0.kk1, t1.kk0  (24 loads; wait to 8 => t0 landed)
  STGA(0, 0) STGB(0, 0)
  STGA(32, 8192) STGB(32, 8192)
  STGA(64, 16384) STGB(64, 16384)
  WAITV(8)
  __builtin_amdgcn_s_barrier();

  for (int t = 0; t < NT; ++t) {
    const int bX = (t & 1) << 14;                    // elems: 0 or 16384
    const int bY = bX ^ 16384;
    const int kc1 = (t + 1) << 6, kc2 = (t + 2) << 6;
    const bool s1 = (t + 1 < NT), s2 = (t + 2 < NT);
    // p0 (mh0,kk0,readB): stage A.kk1(t+1) -> Y.kk1
    GPHASE(0, 0, 1, if (s1) STGA(kc1 + 32, bY + 8192), )
    // p1 (mh1,kk0): stage B.kk1(t+1) -> Y.kk1; tail lands (t+1).kk0
    GPHASE(1, 0, 0, if (s1) STGB(kc1 + 32, bY + 8192),
           if (s1) { WAITV(8) } else { WAITV(0) })
    // p2 (mh0,kk1,readB): stage A.kk0(t+2) -> X.kk0
    GPHASE(0, 1, 1, if (s2) STGA(kc2, bX), )
    // p3 (mh1,kk1): stage B.kk0(t+2) -> X.kk0; tail lands (t+1).kk1
    GPHASE(1, 1, 0, if (s2) STGB(kc2, bX),
           if (s2) { WAITV(8) } else { WAITV(0) })
  }

  if constexpr (MODE == 0) {
#pragma unroll
    for (int mi = 0; mi < 8; ++mi) {
      const int gr = m0 + wm * 128 + mi * 16 + g * 4;
#pragma unroll
      for (int n = 0; n < 8; ++n) {
        const int gc = n0 + wn * 128 + n * 16 + l15;
#pragma unroll
        for (int r = 0; r < 4; ++r)
          C[(size_t)(gr + r) * N + gc] = acc[mi][n][r];
      }
    }
  } else {
    if (nt >= 24) {
      // v block: plain bf16 write into C1v [4096][2048]
#pragma unroll
      for (int mi = 0; mi < 8; ++mi) {
        const int gr = m0 + wm * 128 + mi * 16 + g * 4;
#pragma unroll
        for (int n = 0; n < 8; ++n) {
          const int gc = n0 - 6144 + wn * 128 + n * 16 + l15;
#pragma unroll
          for (int r = 0; r < 4; ++r)
            C[(size_t)(gr + r) * 2048 + gc] = __float2bfloat16(acc[mi][n][r]);
        }
      }
    } else {
      // q/k block: fused RMSNorm + RoPE, write Qb/Kb in permuted (c-space) layout.
      const bool isq = (nt < 16);
      const int head = isq ? nt : (nt - 16);
      const float* wgt = isq ? qw : kw;
      float* red = (float*)lds;    // [256][2] partial sums (staging LDS dead)
      __builtin_amdgcn_s_barrier();
#pragma unroll
      for (int mi = 0; mi < 8; ++mi) {
        float ps[4];
#pragma unroll
        for (int r = 0; r < 4; ++r) {
          float s = 0.f;
#pragma unroll
          for (int n = 0; n < 8; ++n) s += acc[mi][n][r] * acc[mi][n][r];
#pragma unroll
          for (int mm = 1; mm < 16; mm <<= 1) s += __shfl_xor(s, mm);
          ps[r] = s;
        }
        if (l15 == 0) {
          const int rb = wm * 128 + mi * 16 + g * 4;
#pragma unroll
          for (int r = 0; r < 4; ++r) red[(rb + r) * 2 + wn] = ps[r];
        }
      }
      __syncthreads();
      float rms[8][4];
#pragma unroll
      for (int mi = 0; mi < 8; ++mi)
#pragma unroll
        for (int r = 0; r < 4; ++r) {
          const int row = wm * 128 + mi * 16 + g * 4 + r;
          const float2 p = *(const float2*)&red[row * 2];
          rms[mi][r] = rsqrtf((p.x + p.y) * (1.f / 256.f) + 1e-6f);
        }
#pragma unroll
      for (int mi = 0; mi < 8; ++mi) {
#pragma unroll
        for (int r = 0; r < 4; ++r) {
          const int grow = m0 + wm * 128 + mi * 16 + g * 4 + r;
          const int tt = grow & 2047, bb = grow >> 11;
          const float rm = rms[mi][r];
          BF* orow = (isq ? Qb + ((size_t)(bb * 16 + head) * 2048 + tt) * 256
                          : Kb + ((size_t)(bb * 8 + head) * 2048 + tt) * 256);
#pragma unroll
          for (int nn = 0; nn < 4; ++nn) {
            const int n = (nn & 1) | ((nn & 2) << 1);        // 0,1,4,5
            const int dlo = (wn * 2 + (n >> 2)) * 32 + (n & 1) * 16 + l15;
            const float cc = cosl[tt * 128 + dlo];
            const float ss = sinl[tt * 128 + dlo];
            const float xl = acc[mi][n][r] * rm * wgt[dlo];
            const float xh = acc[mi][n + 2][r] * rm * wgt[dlo + 128];
            const int cbase = wn * 128 + n * 16 + l15;
            orow[cbase]      = __float2bfloat16(xl * cc - xh * ss);
            orow[cbase + 32] = __float2bfloat16(xh * cc + xl * ss);
          }
        }
      }
    }
  }
}

__global__ __launch_bounds__(256, 1) void gemm_qkv(const BF* __restrict__ A,
                                                   const BF* __restrict__ Bm,
                                                   BF* __restrict__ C1v,
                                                   BF* __restrict__ Qb, BF* __restrict__ Kb,
                                                   const float* __restrict__ cosl,
                                                   const float* __restrict__ sinl,
                                                   const float* __restrict__ qw,
                                                   const float* __restrict__ kw,
                                                   int M, int N, int K, int lda, int ldb) {
  gemm256_body<BF, 1>(A, Bm, C1v, M, N, K, lda, ldb, Qb, Kb, cosl, sinl, qw, kw);
}
__global__ __launch_bounds__(256, 1) void gemm_out(const BF* __restrict__ A,
                                                   const BF* __restrict__ Bm,
                                                   float* __restrict__ C,
                                                   int M, int N, int K, int lda, int ldb) {
  gemm256_body<float, 0>(A, Bm, C, M, N, K, lda, ldb,
                         nullptr, nullptr, nullptr, nullptr, nullptr, nullptr);
}

// ---------------------------------------------------------------- V transpose (vectorized)
// C1v [b*2048+t][2048] -> Vt [b*8+kv][d 256][t 2048]
__global__ __launch_bounds__(256) void vtrans(const BF* __restrict__ C1v, BF* __restrict__ Vt) {
  __shared__ BF tile[64][68];
  const int bz = blockIdx.z;
  const int tt = blockIdx.x;
  const int dt = blockIdx.y;
  const int tid = threadIdx.x;
  const int r16 = tid >> 4;
  const int c16 = tid & 15;
  const int b = bz >> 3, kv = bz & 7;
#pragma unroll
  for (int p = 0; p < 4; ++p) {
    const int tr = p * 16 + r16;
    const int t = tt * 64 + tr;
    const int d = dt * 64 + c16 * 4;
    *(ushort4*)&tile[tr][c16 * 4] =
        *(const ushort4*)&C1v[((size_t)(b * 2048 + t)) * 2048 + kv * 256 + d];
  }
  __syncthreads();
#pragma unroll
  for (int p = 0; p < 4; ++p) {
    const int dr = p * 16 + r16;
    const int d = dt * 64 + dr;
    const int t4 = c16 * 4;
    ushort4 o;
    o.x = *(const unsigned short*)&tile[t4 + 0][dr];
    o.y = *(const unsigned short*)&tile[t4 + 1][dr];
    o.z = *(const unsigned short*)&tile[t4 + 2][dr];
    o.w = *(const unsigned short*)&tile[t4 + 3][dr];
    *(ushort4*)&Vt[((size_t)bz * 256 + d) * 2048 + tt * 64 + t4] = o;
  }
}

// ---------------------------------------------------------------- flash attention (round-9 body)
// Q/K are in permuted d-space (c-space) -- QK^T invariant.  V untouched.
__global__ __launch_bounds__(512, 1) void attn_fwd(const BF* __restrict__ Q,
                                                   const BF* __restrict__ K,
                                                   const BF* __restrict__ Vt,
                                                   BF* __restrict__ O) {
  __shared__ __align__(16) BF Ks[64 * 256];
  __shared__ __align__(16) BF Vs[256 * 64];
  __shared__ __align__(16) BF Ps[8][1024];
  const int tid = threadIdx.x;
  const int lane = tid & 63;
  const int w = tid >> 6;
  const int wh = w >> 2;
  const int wq = w & 3;
  const int l15 = lane & 15;
  const int g = lane >> 4;
  const int qt = blockIdx.x;
  const int bp = blockIdx.y;
  const int b = bp >> 3, kvh = bp & 7;
  const int h = kvh * 2 + wh;
  const int q0 = qt << 6;
  const BF* Qb = Q + ((size_t)(b * 16 + h) * 2048 + q0) * 256;
  const BF* Kb = K + (size_t)(b * 8 + kvh) * 2048 * 256;
  const BF* Vb = Vt + (size_t)(b * 8 + kvh) * 256 * 2048;

  short8 qf[8];
  {
    const BF* qr = Qb + (wq * 16 + l15) * 256 + g * 8;
#pragma unroll
    for (int kk = 0; kk < 8; ++kk) qf[kk] = *(const short8*)(qr + kk * 32);
  }
  f32x4 oacc[16];
#pragma unroll
  for (int i = 0; i < 16; ++i) oacc[i] = (f32x4){0.f, 0.f, 0.f, 0.f};
  float m_r[4] = {-1e30f, -1e30f, -1e30f, -1e30f};
  float l_r[4] = {0.f, 0.f, 0.f, 0.f};

  const int kt_lo = (q0 > 1023) ? ((q0 - 1023) >> 6) : 0;
  for (int kt = kt_lo; kt <= qt; ++kt) {
    const int tk = kt << 6;
#pragma unroll
    for (int i = 0; i < 4; ++i) {
      const int li = w * 4 + i;
      {
        const int row = li * 2 + (lane >> 5);
        const int ch = lane & 31;
        gll16(Kb + (size_t)(tk + row) * 256 + ((ch ^ (row & 7)) << 3), Ks + li * 512);
      }
      {
        const int row = li * 8 + (lane >> 3);
        const int ch = lane & 7;
        gll16(Vb + (size_t)row * 2048 + tk + ((ch ^ (row & 7)) << 3), Vs + li * 512);
      }
    }
    __syncthreads();

    f32x4 sa[4];
#pragma unroll
    for (int i2 = 0; i2 < 4; ++i2) sa[i2] = (f32x4){0.f, 0.f, 0.f, 0.f};
#pragma unroll
    for (int kk = 0; kk < 8; ++kk) {
      const int d = kk * 32 + g * 8;
#pragma unroll
      for (int blk = 0; blk < 4; ++blk) {
        const int row = blk * 16 + l15;
        const short8 kf = *(const short8*)&Ks[row * 256 + (d ^ ((row & 7) << 3))];
        sa[blk] = __builtin_amdgcn_mfma_f32_16x16x32_bf16(qf[kk], kf, sa[blk], 0, 0, 0);
      }
    }

    float al4[4];
#pragma unroll
    for (int r = 0; r < 4; ++r) {
      const int qi = q0 + wq * 16 + g * 4 + r;
      float pv[4];
      float tmax = -1e30f;
#pragma unroll
      for (int blk = 0; blk < 4; ++blk) {
        const int ki = tk + blk * 16 + l15;
        float sv = sa[blk][r] * 0.0625f;
        const bool ok = (ki <= qi) && (qi - ki < 1024);
        sv = ok ? sv : -1e30f;
        pv[blk] = sv;
        tmax = fmaxf(tmax, sv);
      }
#pragma unroll
      for (int mm = 1; mm < 16; mm <<= 1) tmax = fmaxf(tmax, __shfl_xor(tmax, mm));
      const float mn = fmaxf(m_r[r], tmax);
      const float alpha = __expf(m_r[r] - mn);
      float tsum = 0.f;
#pragma unroll
      for (int blk = 0; blk < 4; ++blk) {
        const float p = __expf(pv[blk] - mn);
        pv[blk] = p;
        tsum += p;
      }
#pragma unroll
      for (int mm = 1; mm < 16; mm <<= 1) tsum += __shfl_xor(tsum, mm);
      l_r[r] = l_r[r] * alpha + tsum;
      m_r[r] = mn;
      al4[r] = alpha;
      const int prow = g * 4 + r;
#pragma unroll
      for (int blk = 0; blk < 4; ++blk) {
        const int col = blk * 16 + l15;
        Ps[w][prow * 64 + (col ^ ((prow & 7) << 3))] = __float2bfloat16(pv[blk]);
      }
    }
#pragma unroll
    for (int db = 0; db < 16; ++db)
#pragma unroll
      for (int r = 0; r < 4; ++r) oacc[db][r] *= al4[r];

#pragma unroll
    for (int kk2 = 0; kk2 < 2; ++kk2) {
      const int k8 = kk2 * 32 + g * 8;
      const short8 pf = *(const short8*)&Ps[w][l15 * 64 + (k8 ^ ((l15 & 7) << 3))];
#pragma unroll
      for (int db = 0; db < 16; ++db) {
        const int vrow = db * 16 + l15;
        const short8 vf = *(const short8*)&Vs[vrow * 64 + (k8 ^ ((vrow & 7) << 3))];
        oacc[db] = __builtin_amdgcn_mfma_f32_16x16x32_bf16(pf, vf, oacc[db], 0, 0, 0);
      }
    }
    __syncthreads();
  }

#pragma unroll
  for (int r = 0; r < 4; ++r) l_r[r] = 1.f / l_r[r];
  const size_t orow0 = (size_t)(b * 2048 + q0 + wq * 16 + g * 4);
#pragma unroll
  for (int r = 0; r < 4; ++r) {
    BF* op = O + (orow0 + r) * 4160 + h * 256 + l15;
#pragma unroll
    for (int db = 0; db < 16; ++db) op[db * 16] = __float2bfloat16(oacc[db][r] * l_r[r]);
  }
}

// ---------------------------------------------------------------- launcher
// ws layout (bytes), lifetimes verified disjoint per step:
//   [0,62914560)           Wqkv  (read by gemm_qkv)      -> after: Vt@0 (16MB), AO@16777216 (34MB)
//   [62914560,94371840)    Xbf   (read by gemm_qkv)
//   [94371840,127926272)   Qb    (written by gemm_qkv epilogue)
//   [127926272,144703488)  Kb
//   [144703488,161480704)  C1v   [4096][2048]
//   [161480704,193429504)  Wo padded (written up-front, read by gemm_out)
extern "C" void kernel_launch(void* const* d_in, const int* in_sizes, int n_in,
                              void* d_out, int out_size, void* d_ws, size_t ws_size,
                              hipStream_t stream) {
  (void)in_sizes; (void)n_in; (void)out_size;
  const float* x    = (const float*)d_in[0];
  const float* cosl = (const float*)d_in[3];   // reference uses LOCAL tables for q and k
  const float* sinl = (const float*)d_in[4];
  const float* wq   = (const float*)d_in[6];
  const float* wk   = (const float*)d_in[7];
  const float* wv   = (const float*)d_in[8];
  const float* wo   = (const float*)d_in[9];
  const float* qw   = (const float*)d_in[10];
  const float* kw   = (const float*)d_in[11];
  float* out = (float*)d_out;
  char* ws = (char*)d_ws;
  if (ws_size < 193429504ull) return;

  BF* Wqkv = (BF*)(ws + 0);
  BF* Xbf  = (BF*)(ws + 62914560);
  BF* Qb   = (BF*)(ws + 94371840);
  BF* Kb   = (BF*)(ws + 127926272);
  BF* C1v  = (BF*)(ws + 144703488);
  BF* Wo   = (BF*)(ws + 161480704);
  BF* Vt   = (BF*)(ws + 0);            // alias: Wqkv dead after gemm_qkv
  BF* AO   = (BF*)(ws + 16777216);     // alias: within dead Wqkv region, after Vt

  hipFuncSetAttribute(reinterpret_cast<const void*>(gemm_qkv),
                      hipFuncAttributeMaxDynamicSharedMemorySize, 131072);
  hipFuncSetAttribute(reinterpret_cast<const void*>(gemm_out),
                      hipFuncAttributeMaxDynamicSharedMemorySize, 131072);

  cvt_fused<<<2048, 256, 0, stream>>>(x, wq, wk, wv, wo, Xbf, Wqkv, Wo);

  gemm_qkv<<<512, 256, 131072, stream>>>(Xbf, Wqkv, C1v, Qb, Kb, cosl, sinl, qw, kw,
                                         4096, 8192, 3840, 3840, 3840);
  vtrans<<<dim3(32, 4, 16), 256, 0, stream>>>(C1v, Vt);
  attn_fwd<<<dim3(32, 16), 512, 0, stream>>>(Qb, Kb, Vt, AO);
  gemm_out<<<240, 256, 131072, stream>>>(AO, Wo, out, 4096, 3840, 4096, 4160, 4160);
}

// Round 15
// 560.579 us; speedup vs baseline: 1.1972x; 1.1972x over previous
//
#include <hip/hip_runtime.h>
#include <hip/hip_bf16.h>

typedef __hip_bfloat16 BF;
typedef __attribute__((ext_vector_type(8))) short short8;
typedef __attribute__((ext_vector_type(4))) float f32x4;

#define DEV __device__ __forceinline__

// ---------------------------------------------------------------- helpers
DEV void gll16(const BF* g, BF* l) {
  __builtin_amdgcn_global_load_lds(
      (const __attribute__((address_space(1))) void*)g,
      (__attribute__((address_space(3))) void*)l, 16, 0, 0);
}

DEV unsigned short bfbits(float f) {
  BF b = __float2bfloat16(f);
  return *reinterpret_cast<unsigned short*>(&b);
}

DEV ushort4 cvt4(const float4 v) {
  return make_ushort4(bfbits(v.x), bfbits(v.y), bfbits(v.z), bfbits(v.w));
}

// rope-pair permutation: orig dim d (0..255) -> gemm column c, so that pairs
// (d, d+128) land in the same thread (acc slots n and n+2).  QK^T is invariant
// to a consistent d-permutation of Q and K, so attn consumes c-space directly.
DEV int rope_perm(int d) {
  return (d < 128) ? ((d >> 5) * 64 + (d & 31))
                   : (((d - 128) >> 5) * 64 + 32 + ((d - 128) & 31));
}

// ---------------------------------------------------------------- fused f32 -> bf16
// x, wq(perm), wk(perm), wv, wo(pad).  float4 ranges:
// x[0,3932160) wq[..7864320) wk[..9830400) wv[..11796480) wo[..15728640)
__global__ void cvt_fused(const float* __restrict__ x, const float* __restrict__ wq,
                          const float* __restrict__ wk, const float* __restrict__ wv,
                          const float* __restrict__ wo,
                          BF* __restrict__ Xbf, BF* __restrict__ Wqkv, BF* __restrict__ Wo) {
  const int stride = gridDim.x * blockDim.x;
  for (int i = blockIdx.x * blockDim.x + threadIdx.x; i < 15728640; i += stride) {
    if (i < 3932160) {
      ((ushort4*)Xbf)[i] = cvt4(((const float4*)x)[i]);
    } else if (i < 7864320) {
      const int off = i - 3932160;
      const int row = off / 960, col = off - row * 960;
      const int nrow = (row & ~255) | rope_perm(row & 255);
      ((ushort4*)Wqkv)[nrow * 960 + col] = cvt4(((const float4*)wq)[off]);
    } else if (i < 9830400) {
      const int off = i - 7864320;
      const int row = off / 960, col = off - row * 960;
      const int nrow = (row & ~255) | rope_perm(row & 255);
      ((ushort4*)(Wqkv + 4096 * 3840))[nrow * 960 + col] = cvt4(((const float4*)wk)[off]);
    } else if (i < 11796480) {
      const int off = i - 9830400;
      ((ushort4*)(Wqkv + 6144 * 3840))[off] = cvt4(((const float4*)wv)[off]);
    } else {
      const int off = i - 11796480;
      const int r = off >> 10, c = off & 1023;
      ((ushort4*)Wo)[r * 1040 + c] = cvt4(((const float4*)wo)[off]);
    }
  }
}

// ---------------------------------------------------------------- 256^2 8-phase GEMM (B^T)
// Round-7 K-loop (best measured; 7 scheduling experiments all null/regressed -
// structure is pinned at ~48% MfmaUtil, do not touch).  MODE 0: plain C write.
// MODE 1 (qkv) epilogues by nt:
//   nt<16:  q head -> fused RMSNorm+RoPE -> Qb (permuted c-space)
//   16..23: k head -> same -> Kb
//   24..31: v head -> DIRECT transposed write into Vt[(b*8+kv)][d][t] via
//           ushort4 along t (acc r=0..3 are consecutive t) -- replaces the
//           old scalar C1v write + separate vtrans kernel (saves 66 MB traffic).
#define PHASE(MH, KK, READB, STAGE, TAIL)                                            \
  {                                                                                  \
    short8 af[4];                                                                    \
    const BF* Ap = Ax + (KK)*8192;                                                   \
    _Pragma("unroll") for (int m = 0; m < 4; ++m)                                    \
        af[m] = *(const short8*)&Ap[(wm*128 + (MH)*64 + m*16 + l15) * 32 + rd8];     \
    if (READB) {                                                                     \
      const BF* Bp = Bx + (KK)*8192;                                                 \
      _Pragma("unroll") for (int n = 0; n < 4; ++n)                                  \
          breg[n] = *(const short8*)&Bp[(wn*64 + n*16 + l15) * 32 + rd8];            \
    }                                                                                \
    STAGE                                                                            \
    __builtin_amdgcn_s_barrier();                                                    \
    asm volatile("s_waitcnt lgkmcnt(0)" ::: "memory");                               \
    __builtin_amdgcn_sched_barrier(0);                                               \
    __builtin_amdgcn_s_setprio(1);                                                   \
    _Pragma("unroll") for (int m = 0; m < 4; ++m)                                    \
      _Pragma("unroll") for (int n = 0; n < 4; ++n)                                  \
        acc[(MH)*4 + m][n] =                                                         \
            __builtin_amdgcn_mfma_f32_16x16x32_bf16(af[m], breg[n], acc[(MH)*4+m][n], 0, 0, 0); \
    __builtin_amdgcn_s_setprio(0);                                                   \
    TAIL                                                                             \
    __builtin_amdgcn_s_barrier();                                                    \
  }

#define STG2(SRC, RST, DST) { gll16((SRC), (DST)); gll16((SRC) + (RST), (DST) + 4096); }

template <typename CT, int MODE>
DEV void gemm256_body(const BF* __restrict__ A, const BF* __restrict__ Bm,
                      CT* __restrict__ C, const int M, const int N, const int K,
                      const int lda, const int ldb,
                      BF* __restrict__ Qb, BF* __restrict__ Kb,
                      const float* __restrict__ cosl, const float* __restrict__ sinl,
                      const float* __restrict__ qw, const float* __restrict__ kw) {
  extern __shared__ __align__(16) BF lds[];
  BF* ldsA = lds;
  BF* ldsB = lds + 32768;
  const int ntl = N >> 8;
  const int mtl = M >> 8;
  int mt, nt;
  if (mtl == 16 && ntl == 32) {
    // 2-D chunked XCD raster (FETCH 507->184 MB verified round 7)
    const int x = blockIdx.x & 7;
    const int c = blockIdx.x >> 3;
    mt = ((x >> 2) << 3) + (c >> 3);
    nt = ((x & 3) << 3) + (c & 7);
  } else {
    const int cpx = gridDim.x >> 3;
    const int swzb = (blockIdx.x & 7) * cpx + (blockIdx.x >> 3);
    mt = swzb / ntl;
    nt = swzb % ntl;
  }
  const int m0 = mt << 8, n0 = nt << 8;
  const int tid = threadIdx.x, lane = tid & 63, w = tid >> 6;
  const int l15 = lane & 15, g = lane >> 4;
  const int wm = w >> 2, wn = w & 3;
  const int rd8 = (g ^ ((l15 >> 1) & 3)) << 3;
  const int trow = tid >> 2;
  const int scol = ((lane & 3) ^ ((lane >> 3) & 3)) << 3;
  const BF* aS = A + (size_t)(m0 + trow) * lda + scol;
  const BF* bS = Bm + (size_t)(n0 + trow) * ldb + scol;
  const size_t rstpA = (size_t)128 * lda;
  const size_t rstpB = (size_t)128 * ldb;
  BF* dA = ldsA + w * 512;
  BF* dB = ldsB + w * 512;
  const int NT = K >> 6;

  f32x4 acc[8][4];
#pragma unroll
  for (int m = 0; m < 8; ++m)
#pragma unroll
    for (int n = 0; n < 4; ++n) acc[m][n] = (f32x4){0.f, 0.f, 0.f, 0.f};
  short8 breg[4];

  STG2(aS, rstpA, dA);
  STG2(bS, rstpB, dB);
  STG2(aS + 32, rstpA, dA + 8192);
  STG2(bS + 32, rstpB, dB + 8192);
  STG2(aS + 64, rstpA, dA + 16384);
  STG2(bS + 64, rstpB, dB + 16384);
  asm volatile("s_waitcnt vmcnt(8)" ::: "memory");
  __builtin_amdgcn_sched_barrier(0);
  __builtin_amdgcn_s_barrier();

  for (int t = 0; t < NT; ++t) {
    const int bX = (t & 1) << 14;
    const int bY = bX ^ 16384;
    const BF* Ax = ldsA + bX;
    const BF* Bx = ldsB + bX;
    const int kc1 = (t + 1) << 6, kc2 = (t + 2) << 6;
    const bool s1 = (t + 1 < NT), s2 = (t + 2 < NT);
    PHASE(0, 0, 1, if (s1) STG2(aS + kc1 + 32, rstpA, dA + bY + 8192);, )
    PHASE(1, 0, 0, if (s1) STG2(bS + kc1 + 32, rstpB, dB + bY + 8192);,
          { asm volatile("s_waitcnt vmcnt(8)" ::: "memory");
            __builtin_amdgcn_sched_barrier(0); } )
    PHASE(0, 1, 1, if (s2) STG2(aS + kc2, rstpA, dA + bX);, )
    PHASE(1, 1, 0, if (s2) STG2(bS + kc2, rstpB, dB + bX);,
          if (s2) { asm volatile("s_waitcnt vmcnt(8)" ::: "memory");
                    __builtin_amdgcn_sched_barrier(0); }
          else    { asm volatile("s_waitcnt vmcnt(0)" ::: "memory");
                    __builtin_amdgcn_sched_barrier(0); } )
  }

  if constexpr (MODE == 0) {
#pragma unroll
    for (int mi = 0; mi < 8; ++mi) {
      const int gr = m0 + wm * 128 + mi * 16 + g * 4;
#pragma unroll
      for (int n = 0; n < 4; ++n) {
        const int gc = n0 + wn * 64 + n * 16 + l15;
#pragma unroll
        for (int r = 0; r < 4; ++r)
          C[(size_t)(gr + r) * N + gc] = acc[mi][n][r];
      }
    }
  } else {
    if (nt >= 24) {
      // v block: direct transposed write into Vt[(b*8+kv)][d 256][t 2048].
      // acc[mi][n][0..3] are 4 consecutive t for fixed d -> one ushort4 store.
      const int kv = nt - 24;
      const int b = m0 >> 11;
      const int tb = m0 & 2047;
      BF* vbase = (BF*)C + (size_t)(b * 8 + kv) * 524288;
#pragma unroll
      for (int mi = 0; mi < 8; ++mi) {
        const int t0 = tb + wm * 128 + mi * 16 + g * 4;
#pragma unroll
        for (int n = 0; n < 4; ++n) {
          const int d = wn * 64 + n * 16 + l15;
          ushort4 o = make_ushort4(bfbits(acc[mi][n][0]), bfbits(acc[mi][n][1]),
                                   bfbits(acc[mi][n][2]), bfbits(acc[mi][n][3]));
          *(ushort4*)&vbase[(size_t)d * 2048 + t0] = o;
        }
      }
    } else {
      // q/k block: fused RMSNorm + RoPE, write Qb/Kb in permuted (c-space) layout.
      const bool isq = (nt < 16);
      const int head = isq ? nt : (nt - 16);
      const float* wgt = isq ? qw : kw;
      float* red = (float*)lds;    // [256][4] partial sums (staging LDS dead)
      __builtin_amdgcn_s_barrier();
#pragma unroll
      for (int mi = 0; mi < 8; ++mi) {
        float ps[4];
#pragma unroll
        for (int r = 0; r < 4; ++r) {
          float s = 0.f;
#pragma unroll
          for (int n = 0; n < 4; ++n) s += acc[mi][n][r] * acc[mi][n][r];
#pragma unroll
          for (int mm = 1; mm < 16; mm <<= 1) s += __shfl_xor(s, mm);
          ps[r] = s;
        }
        if (l15 == 0) {
          const int rb = wm * 128 + mi * 16 + g * 4;
#pragma unroll
          for (int r = 0; r < 4; ++r) red[(rb + r) * 4 + wn] = ps[r];
        }
      }
      __syncthreads();
      float rms[8][4];
#pragma unroll
      for (int mi = 0; mi < 8; ++mi)
#pragma unroll
        for (int r = 0; r < 4; ++r) {
          const int row = wm * 128 + mi * 16 + g * 4 + r;
          const float4 p = *(const float4*)&red[row * 4];
          rms[mi][r] = rsqrtf((p.x + p.y + p.z + p.w) * (1.f / 256.f) + 1e-6f);
        }
#pragma unroll
      for (int mi = 0; mi < 8; ++mi) {
#pragma unroll
        for (int r = 0; r < 4; ++r) {
          const int grow = m0 + wm * 128 + mi * 16 + g * 4 + r;
          const int tt = grow & 2047, bb = grow >> 11;
          const float rm = rms[mi][r];
          BF* orow = (isq ? Qb + ((size_t)(bb * 16 + head) * 2048 + tt) * 256
                          : Kb + ((size_t)(bb * 8 + head) * 2048 + tt) * 256);
#pragma unroll
          for (int n = 0; n < 2; ++n) {
            const int dlo = wn * 32 + n * 16 + l15;
            const float cc = cosl[tt * 128 + dlo];
            const float ss = sinl[tt * 128 + dlo];
            const float xl = acc[mi][n][r] * rm * wgt[dlo];
            const float xh = acc[mi][n + 2][r] * rm * wgt[dlo + 128];
            const int cbase = wn * 64 + n * 16 + l15;
            orow[cbase]      = __float2bfloat16(xl * cc - xh * ss);
            orow[cbase + 32] = __float2bfloat16(xh * cc + xl * ss);
          }
        }
      }
    }
  }
}

__global__ __launch_bounds__(512, 2) void gemm_qkv(const BF* __restrict__ A,
                                                   const BF* __restrict__ Bm,
                                                   BF* __restrict__ Vt,
                                                   BF* __restrict__ Qb, BF* __restrict__ Kb,
                                                   const float* __restrict__ cosl,
                                                   const float* __restrict__ sinl,
                                                   const float* __restrict__ qw,
                                                   const float* __restrict__ kw,
                                                   int M, int N, int K, int lda, int ldb) {
  gemm256_body<BF, 1>(A, Bm, Vt, M, N, K, lda, ldb, Qb, Kb, cosl, sinl, qw, kw);
}
__global__ __launch_bounds__(512, 2) void gemm_out(const BF* __restrict__ A,
                                                   const BF* __restrict__ Bm,
                                                   float* __restrict__ C,
                                                   int M, int N, int K, int lda, int ldb) {
  gemm256_body<float, 0>(A, Bm, C, M, N, K, lda, ldb,
                         nullptr, nullptr, nullptr, nullptr, nullptr, nullptr);
}

// ---------------------------------------------------------------- flash attention (round-9 body)
// Q/K in permuted d-space (QK^T invariant).  Vt [b*8+kv][d 256][t 2048].
__global__ __launch_bounds__(512, 1) void attn_fwd(const BF* __restrict__ Q,
                                                   const BF* __restrict__ K,
                                                   const BF* __restrict__ Vt,
                                                   BF* __restrict__ O) {
  __shared__ __align__(16) BF Ks[64 * 256];
  __shared__ __align__(16) BF Vs[256 * 64];
  __shared__ __align__(16) BF Ps[8][1024];
  const int tid = threadIdx.x;
  const int lane = tid & 63;
  const int w = tid >> 6;
  const int wh = w >> 2;
  const int wq = w & 3;
  const int l15 = lane & 15;
  const int g = lane >> 4;
  const int qt = blockIdx.x;
  const int bp = blockIdx.y;
  const int b = bp >> 3, kvh = bp & 7;
  const int h = kvh * 2 + wh;
  const int q0 = qt << 6;
  const BF* Qb = Q + ((size_t)(b * 16 + h) * 2048 + q0) * 256;
  const BF* Kb = K + (size_t)(b * 8 + kvh) * 2048 * 256;
  const BF* Vb = Vt + (size_t)(b * 8 + kvh) * 256 * 2048;

  short8 qf[8];
  {
    const BF* qr = Qb + (wq * 16 + l15) * 256 + g * 8;
#pragma unroll
    for (int kk = 0; kk < 8; ++kk) qf[kk] = *(const short8*)(qr + kk * 32);
  }
  f32x4 oacc[16];
#pragma unroll
  for (int i = 0; i < 16; ++i) oacc[i] = (f32x4){0.f, 0.f, 0.f, 0.f};
  float m_r[4] = {-1e30f, -1e30f, -1e30f, -1e30f};
  float l_r[4] = {0.f, 0.f, 0.f, 0.f};

  const int kt_lo = (q0 > 1023) ? ((q0 - 1023) >> 6) : 0;
  for (int kt = kt_lo; kt <= qt; ++kt) {
    const int tk = kt << 6;
#pragma unroll
    for (int i = 0; i < 4; ++i) {
      const int li = w * 4 + i;
      {
        const int row = li * 2 + (lane >> 5);
        const int ch = lane & 31;
        gll16(Kb + (size_t)(tk + row) * 256 + ((ch ^ (row & 7)) << 3), Ks + li * 512);
      }
      {
        const int row = li * 8 + (lane >> 3);
        const int ch = lane & 7;
        gll16(Vb + (size_t)row * 2048 + tk + ((ch ^ (row & 7)) << 3), Vs + li * 512);
      }
    }
    __syncthreads();

    f32x4 sa[4];
#pragma unroll
    for (int i2 = 0; i2 < 4; ++i2) sa[i2] = (f32x4){0.f, 0.f, 0.f, 0.f};
#pragma unroll
    for (int kk = 0; kk < 8; ++kk) {
      const int d = kk * 32 + g * 8;
#pragma unroll
      for (int blk = 0; blk < 4; ++blk) {
        const int row = blk * 16 + l15;
        const short8 kf = *(const short8*)&Ks[row * 256 + (d ^ ((row & 7) << 3))];
        sa[blk] = __builtin_amdgcn_mfma_f32_16x16x32_bf16(qf[kk], kf, sa[blk], 0, 0, 0);
      }
    }

    float al4[4];
#pragma unroll
    for (int r = 0; r < 4; ++r) {
      const int qi = q0 + wq * 16 + g * 4 + r;
      float pv[4];
      float tmax = -1e30f;
#pragma unroll
      for (int blk = 0; blk < 4; ++blk) {
        const int ki = tk + blk * 16 + l15;
        float sv = sa[blk][r] * 0.0625f;
        const bool ok = (ki <= qi) && (qi - ki < 1024);
        sv = ok ? sv : -1e30f;
        pv[blk] = sv;
        tmax = fmaxf(tmax, sv);
      }
#pragma unroll
      for (int mm = 1; mm < 16; mm <<= 1) tmax = fmaxf(tmax, __shfl_xor(tmax, mm));
      const float mn = fmaxf(m_r[r], tmax);
      const float alpha = __expf(m_r[r] - mn);
      float tsum = 0.f;
#pragma unroll
      for (int blk = 0; blk < 4; ++blk) {
        const float p = __expf(pv[blk] - mn);
        pv[blk] = p;
        tsum += p;
      }
#pragma unroll
      for (int mm = 1; mm < 16; mm <<= 1) tsum += __shfl_xor(tsum, mm);
      l_r[r] = l_r[r] * alpha + tsum;
      m_r[r] = mn;
      al4[r] = alpha;
      const int prow = g * 4 + r;
#pragma unroll
      for (int blk = 0; blk < 4; ++blk) {
        const int col = blk * 16 + l15;
        Ps[w][prow * 64 + (col ^ ((prow & 7) << 3))] = __float2bfloat16(pv[blk]);
      }
    }
#pragma unroll
    for (int db = 0; db < 16; ++db)
#pragma unroll
      for (int r = 0; r < 4; ++r) oacc[db][r] *= al4[r];

#pragma unroll
    for (int kk2 = 0; kk2 < 2; ++kk2) {
      const int k8 = kk2 * 32 + g * 8;
      const short8 pf = *(const short8*)&Ps[w][l15 * 64 + (k8 ^ ((l15 & 7) << 3))];
#pragma unroll
      for (int db = 0; db < 16; ++db) {
        const int vrow = db * 16 + l15;
        const short8 vf = *(const short8*)&Vs[vrow * 64 + (k8 ^ ((vrow & 7) << 3))];
        oacc[db] = __builtin_amdgcn_mfma_f32_16x16x32_bf16(pf, vf, oacc[db], 0, 0, 0);
      }
    }
    __syncthreads();
  }

#pragma unroll
  for (int r = 0; r < 4; ++r) l_r[r] = 1.f / l_r[r];
  const size_t orow0 = (size_t)(b * 2048 + q0 + wq * 16 + g * 4);
#pragma unroll
  for (int r = 0; r < 4; ++r) {
    BF* op = O + (orow0 + r) * 4160 + h * 256 + l15;
#pragma unroll
    for (int db = 0; db < 16; ++db) op[db * 16] = __float2bfloat16(oacc[db][r] * l_r[r]);
  }
}

// ---------------------------------------------------------------- launcher
// ws layout (bytes), lifetimes verified disjoint per step:
//   [0,62914560)           Wqkv  (read by gemm_qkv)   -> after gemm_qkv: AO@0 (34MB)
//   [62914560,94371840)    Xbf   (read by gemm_qkv)
//   [94371840,127926272)   Qb    (written by gemm_qkv epilogue)
//   [127926272,144703488)  Kb
//   [144703488,161480704)  Vt    (written by gemm_qkv v-epilogue; NOT aliasing Wqkv/Xbf)
//   [161480704,193429504)  Wo padded (written up-front, read by gemm_out)
extern "C" void kernel_launch(void* const* d_in, const int* in_sizes, int n_in,
                              void* d_out, int out_size, void* d_ws, size_t ws_size,
                              hipStream_t stream) {
  (void)in_sizes; (void)n_in; (void)out_size;
  const float* x    = (const float*)d_in[0];
  const float* cosl = (const float*)d_in[3];   // reference uses LOCAL tables for q and k
  const float* sinl = (const float*)d_in[4];
  const float* wq   = (const float*)d_in[6];
  const float* wk   = (const float*)d_in[7];
  const float* wv   = (const float*)d_in[8];
  const float* wo   = (const float*)d_in[9];
  const float* qw   = (const float*)d_in[10];
  const float* kw   = (const float*)d_in[11];
  float* out = (float*)d_out;
  char* ws = (char*)d_ws;
  if (ws_size < 193429504ull) return;

  BF* Wqkv = (BF*)(ws + 0);
  BF* Xbf  = (BF*)(ws + 62914560);
  BF* Qb   = (BF*)(ws + 94371840);
  BF* Kb   = (BF*)(ws + 127926272);
  BF* Vt   = (BF*)(ws + 144703488);
  BF* Wo   = (BF*)(ws + 161480704);
  BF* AO   = (BF*)(ws + 0);            // alias: Wqkv+Xbf dead after gemm_qkv

  hipFuncSetAttribute(reinterpret_cast<const void*>(gemm_qkv),
                      hipFuncAttributeMaxDynamicSharedMemorySize, 131072);
  hipFuncSetAttribute(reinterpret_cast<const void*>(gemm_out),
                      hipFuncAttributeMaxDynamicSharedMemorySize, 131072);

  cvt_fused<<<2048, 256, 0, stream>>>(x, wq, wk, wv, wo, Xbf, Wqkv, Wo);

  gemm_qkv<<<512, 512, 131072, stream>>>(Xbf, Wqkv, Vt, Qb, Kb, cosl, sinl, qw, kw,
                                         4096, 8192, 3840, 3840, 3840);
  attn_fwd<<<dim3(32, 16), 512, 0, stream>>>(Qb, Kb, Vt, AO);
  gemm_out<<<240, 512, 131072, stream>>>(AO, Wo, out, 4096, 3840, 4096, 4160, 4160);
}